// Round 1
// baseline (1125.263 us; speedup 1.0000x reference)
//
#include <hip/hip_runtime.h>

#define N 8192
#define F_IN 256
#define F_OUT 64
#define ALPHA 0.2f
#define NEG_INF -9.0e15f

// Kernel 1: Wh = h @ W ; s1 = Wh @ a1 ; s2 = Wh @ a2
// grid = N blocks, 64 threads (1 wave). lane = output feature.
__global__ __launch_bounds__(64) void wh_kernel(
    const float* __restrict__ h,
    const float* __restrict__ W,
    const float* __restrict__ a,
    float* __restrict__ Wh,
    float* __restrict__ s1,
    float* __restrict__ s2) {
    const int i = blockIdx.x;
    const int f = threadIdx.x;  // 0..63
    const float* hrow = h + (size_t)i * F_IN;
    float acc = 0.f;
#pragma unroll 8
    for (int k = 0; k < F_IN; ++k) {
        acc += hrow[k] * W[k * F_OUT + f];
    }
    Wh[(size_t)i * F_OUT + f] = acc;
    float p1 = acc * a[f];
    float p2 = acc * a[F_OUT + f];
    // wave64 shuffle reduction
#pragma unroll
    for (int off = 32; off > 0; off >>= 1) {
        p1 += __shfl_down(p1, off, 64);
        p2 += __shfl_down(p2, off, 64);
    }
    if (f == 0) {
        s1[i] = p1;
        s2[i] = p2;
    }
}

// Kernel 2: one block per output row i. 256 threads = 4 waves.
// Pass 1: scores -> LDS, block max. Pass 2a: weights + sum. Pass 2b: aggregate.
__global__ __launch_bounds__(256) void attn_kernel(
    const int* __restrict__ adj,
    const float* __restrict__ Wh,
    const float* __restrict__ s1,
    const float* __restrict__ s2,
    float* __restrict__ out) {
    __shared__ float sc[N];        // 32 KB: scores then weights
    __shared__ float red[16];      // block reductions (max, sum)
    __shared__ float accs[4][F_OUT];

    const int i = blockIdx.x;
    const int t = threadIdx.x;     // 0..255
    const int wave = t >> 6;
    const int lane = t & 63;

    const float s1i = s1[i];
    const int* __restrict__ arow = adj + (size_t)i * N;

    // ---- pass 1: masked leaky-relu scores into LDS + local max ----
    float m = NEG_INF;
    for (int j = t; j < N; j += 256) {
        const int aij = arow[j];
        float e = s1i + s2[j];
        e = e > 0.f ? e : ALPHA * e;
        const float scj = (aij > 0) ? e : NEG_INF;
        sc[j] = scj;
        m = fmaxf(m, scj);
    }
#pragma unroll
    for (int off = 32; off > 0; off >>= 1) m = fmaxf(m, __shfl_down(m, off, 64));
    if (lane == 0) red[wave] = m;
    __syncthreads();
    m = fmaxf(fmaxf(red[0], red[1]), fmaxf(red[2], red[3]));

    // ---- pass 2a: weights (overwrite own sc slots) + partial sum ----
    float sw = 0.f;
    for (int j = t; j < N; j += 256) {
        // masked: sc[j]-m ~ -9e15 -> __expf underflows to exactly 0.
        // all-masked row: m == NEG_INF -> arg 0 -> weight 1 (uniform, matches ref).
        const float w = __expf(sc[j] - m);
        sc[j] = w;
        sw += w;
    }
#pragma unroll
    for (int off = 32; off > 0; off >>= 1) sw += __shfl_down(sw, off, 64);
    if (lane == 0) red[8 + wave] = sw;
    __syncthreads();  // also publishes weight writes in sc[]
    sw = red[8] + red[9] + red[10] + red[11];
    const float inv = 1.f / sw;

    // ---- pass 2b: acc[f] = sum_j w[j] * Wh[j][f]; lane=feature, waves stride j ----
    float acc = 0.f;
#pragma unroll 8
    for (int j = wave; j < N; j += 4) {
        const float w = sc[j];                       // LDS broadcast
        acc += w * Wh[(size_t)j * F_OUT + lane];     // coalesced 256B/wave
    }
    accs[wave][lane] = acc;
    __syncthreads();
    if (wave == 0) {
        const float r = accs[0][lane] + accs[1][lane] + accs[2][lane] + accs[3][lane];
        out[(size_t)i * F_OUT + lane] = r * inv;
    }
}

extern "C" void kernel_launch(void* const* d_in, const int* in_sizes, int n_in,
                              void* d_out, int out_size, void* d_ws, size_t ws_size,
                              hipStream_t stream) {
    const float* h   = (const float*)d_in[0];
    const int*   adj = (const int*)d_in[1];
    const float* W   = (const float*)d_in[2];
    const float* a   = (const float*)d_in[3];
    float* out = (float*)d_out;

    // workspace layout: Wh (N*F_OUT f32), s1 (N), s2 (N)
    float* Wh = (float*)d_ws;
    float* s1 = Wh + (size_t)N * F_OUT;
    float* s2 = s1 + N;

    wh_kernel<<<N, 64, 0, stream>>>(h, W, a, Wh, s1, s2);
    attn_kernel<<<N, 256, 0, stream>>>(adj, Wh, s1, s2, out);
}

// Round 2
// 645.511 us; speedup vs baseline: 1.7432x; 1.7432x over previous
//
#include <hip/hip_runtime.h>

#define N 8192
#define F_IN 256
#define F_OUT 64
#define ALPHA 0.2f
#define NEG_INF -9.0e15f

typedef __attribute__((ext_vector_type(8))) short bf16x8;
typedef __attribute__((ext_vector_type(4))) float f32x4;
typedef __attribute__((ext_vector_type(4))) unsigned u32x4;

// f32 -> bf16 with round-to-nearest-even (values are finite, no NaN handling needed)
__device__ __forceinline__ unsigned short f2bf(float x) {
    unsigned u = __float_as_uint(x);
    u = (u + 0x7FFFu + ((u >> 16) & 1u)) >> 16;
    return (unsigned short)u;
}

// ---------------------------------------------------------------------------
// Kernel 1: Wh = h @ W (fp32 exact), s1 = Wh@a1, s2 = Wh@a2, WhT = bf16(Wh)^T
// grid 256 blocks x 256 thr; block owns 32 rows; W staged in LDS (64 KB).
// ---------------------------------------------------------------------------
#define K1_ROWS 32
__global__ __launch_bounds__(256) void wh_kernel(
    const float* __restrict__ h, const float* __restrict__ W,
    const float* __restrict__ a,
    unsigned short* __restrict__ WhT,   // [F_OUT][N] bf16
    float* __restrict__ s1, float* __restrict__ s2) {
    __shared__ float Wl[F_IN * F_OUT];      // 64 KB, [k][f]
    __shared__ float hl[K1_ROWS * F_IN];    // 32 KB, [r][k]
    __shared__ float whl[K1_ROWS][F_OUT];   // 8 KB

    const int t = threadIdx.x;
    const int wave = t >> 6, lane = t & 63;
    const int i0 = blockIdx.x * K1_ROWS;

    // stage W (16384 floats) and h rows (8192 floats), coalesced float4
    for (int it = 0; it < 16; ++it) {
        const int idx = it * 1024 + t * 4;
        *(f32x4*)&Wl[idx] = *(const f32x4*)&W[idx];
    }
    const float* hbase = h + (size_t)i0 * F_IN;
    for (int it = 0; it < 8; ++it) {
        const int idx = it * 1024 + t * 4;
        *(f32x4*)&hl[idx] = *(const f32x4*)&hbase[idx];
    }
    __syncthreads();

    const int f = lane;             // output feature
    const int r0 = wave * 8;        // 8 rows per wave
    float acc[8];
#pragma unroll
    for (int r = 0; r < 8; ++r) acc[r] = 0.f;

#pragma unroll 4
    for (int k = 0; k < F_IN; ++k) {
        const float wv = Wl[k * F_OUT + f];   // 2-way bank alias: free
#pragma unroll
        for (int r = 0; r < 8; ++r)
            acc[r] += hl[(r0 + r) * F_IN + k] * wv;   // LDS broadcast
    }

    const float a1f = a[f], a2f = a[F_OUT + f];
#pragma unroll
    for (int r = 0; r < 8; ++r) {
        whl[r0 + r][f] = acc[r];
        float p1 = acc[r] * a1f, p2 = acc[r] * a2f;
#pragma unroll
        for (int off = 32; off; off >>= 1) {
            p1 += __shfl_down(p1, off, 64);
            p2 += __shfl_down(p2, off, 64);
        }
        if (lane == 0) { s1[i0 + r0 + r] = p1; s2[i0 + r0 + r] = p2; }
    }
    __syncthreads();

    // transposed bf16 write: thread t -> f = t>>2, rows rr0..rr0+7
    {
        const int ff = t >> 2;
        const int rr0 = (t & 3) * 8;
        float v[8];
#pragma unroll
        for (int u = 0; u < 8; ++u) v[u] = whl[rr0 + u][ff];
        u32x4 p;
#pragma unroll
        for (int u = 0; u < 4; ++u)
            p[u] = (unsigned)f2bf(v[2 * u]) | ((unsigned)f2bf(v[2 * u + 1]) << 16);
        *(u32x4*)(WhT + (size_t)ff * N + i0 + rr0) = p;
    }
}

// ---------------------------------------------------------------------------
// Kernel 2: fused mask+softmax+aggregate.
// grid 512 blocks x 256 thr; block owns 16 rows. Phase 1: stream adj strip ->
// LDS bitmask + masked max of s2 (monotonicity). Phase 2: MFMA P@WhT with
// on-the-fly P build in A-fragment layout; ones-column gives rowsums.
// ---------------------------------------------------------------------------
#define ROWS2 16
__global__ __launch_bounds__(256, 2) void attn_kernel(
    const int* __restrict__ adj,
    const unsigned short* __restrict__ WhT,
    const float* __restrict__ s1, const float* __restrict__ s2,
    float* __restrict__ out) {
    __shared__ unsigned bm[ROWS2][257];               // 16.4 KB (pad -> bank m+word)
    __shared__ float partmax[ROWS2][4];
    __shared__ float mrow[ROWS2];
    __shared__ float s1row[ROWS2];
    __shared__ __align__(16) float accbuf[4][ROWS2][F_OUT];  // 16 KB
    __shared__ float rowsums[4][ROWS2];

    const int t = threadIdx.x;
    const int wave = t >> 6, lane = t & 63;
    const int i0 = blockIdx.x * ROWS2;
    const int jb0 = wave * (N / 4);                   // 2048-wide j strip per wave

    // ---------------- phase 1: adj -> bitmask, masked max of s2 ----------------
    float runmax[ROWS2];
#pragma unroll
    for (int r = 0; r < ROWS2; ++r) runmax[r] = -3.0e38f;

    for (int jc = 0; jc < 32; ++jc) {
        const int j = jb0 + jc * 64 + lane;
        const float s2v = s2[j];
        const int wb = (jb0 >> 5) + jc * 2;
#pragma unroll
        for (int r = 0; r < ROWS2; ++r) {
            const int av = adj[(size_t)(i0 + r) * N + j];
            const bool pred = av > 0;
            const unsigned long long bal = __ballot(pred);
            if (lane < 2) bm[r][wb + lane] = (unsigned)(bal >> (lane << 5));
            runmax[r] = fmaxf(runmax[r], pred ? s2v : -3.0e38f);
        }
    }
#pragma unroll
    for (int r = 0; r < ROWS2; ++r) {
        float m = runmax[r];
#pragma unroll
        for (int off = 32; off; off >>= 1) m = fmaxf(m, __shfl_down(m, off, 64));
        if (lane == 0) partmax[r][wave] = m;
    }
    __syncthreads();
    if (t < ROWS2) {
        const float m2 = fmaxf(fmaxf(partmax[t][0], partmax[t][1]),
                               fmaxf(partmax[t][2], partmax[t][3]));
        const float s1v = s1[i0 + t];
        const float x = s1v + m2;                     // -3e38 if no neighbors
        const float e = fmaxf(x, ALPHA * x);          // leaky relu (monotone)
        mrow[t] = fmaxf(e, NEG_INF);                  // no-neighbor row -> NEG_INF
        s1row[t] = s1v;
    }
    __syncthreads();

    // ---------------- phase 2: MFMA P @ WhT over this wave's j strip ----------------
    const int mq = lane & 15, quad = lane >> 4;
    const float s1m = s1row[mq];
    const float mr = mrow[mq];

    f32x4 acc0 = {0.f, 0.f, 0.f, 0.f}, acc1 = acc0, acc2 = acc0, acc3 = acc0, accS = acc0;
    bf16x8 onesf;
#pragma unroll
    for (int jj = 0; jj < 8; ++jj) onesf[jj] = (mq == 0) ? (short)0x3F80 : (short)0;

    for (int c = 0; c < 64; ++c) {
        const int jb = jb0 + c * 32;
        const unsigned mask32 = bm[mq][(jb0 >> 5) + c];
        const unsigned mbyte = mask32 >> (quad * 8);
        const float* s2p = s2 + jb + quad * 8;
        const f32x4 v0 = *(const f32x4*)s2p;
        const f32x4 v1 = *(const f32x4*)(s2p + 4);
        const unsigned short* wp = WhT + (size_t)mq * N + jb + quad * 8;
        const bf16x8 b0 = *(const bf16x8*)(wp + 0 * 16 * N);
        const bf16x8 b1 = *(const bf16x8*)(wp + 1 * 16 * N);
        const bf16x8 b2 = *(const bf16x8*)(wp + 2 * 16 * N);
        const bf16x8 b3 = *(const bf16x8*)(wp + 3 * 16 * N);

        float wv[8];
#pragma unroll
        for (int jj = 0; jj < 8; ++jj) {
            const float s2k = (jj < 4) ? v0[jj] : v1[jj - 4];
            const float x = s1m + s2k;
            const float e = fmaxf(x, ALPHA * x);               // leaky relu
            const float sc = ((mbyte >> jj) & 1u) ? e : NEG_INF;
            wv[jj] = __expf(sc - mr);                          // masked -> exactly 0
        }
        bf16x8 af;
#pragma unroll
        for (int jj = 0; jj < 8; ++jj) af[jj] = (short)f2bf(wv[jj]);

        acc0 = __builtin_amdgcn_mfma_f32_16x16x32_bf16(af, b0, acc0, 0, 0, 0);
        acc1 = __builtin_amdgcn_mfma_f32_16x16x32_bf16(af, b1, acc1, 0, 0, 0);
        acc2 = __builtin_amdgcn_mfma_f32_16x16x32_bf16(af, b2, acc2, 0, 0, 0);
        acc3 = __builtin_amdgcn_mfma_f32_16x16x32_bf16(af, b3, acc3, 0, 0, 0);
        accS = __builtin_amdgcn_mfma_f32_16x16x32_bf16(af, onesf, accS, 0, 0, 0);
    }

    // stash per-wave partials (D layout: row = quad*4+reg, col = lane&15)
#pragma unroll
    for (int r = 0; r < 4; ++r) {
        const int row = quad * 4 + r;
        accbuf[wave][row][0 * 16 + mq] = acc0[r];
        accbuf[wave][row][1 * 16 + mq] = acc1[r];
        accbuf[wave][row][2 * 16 + mq] = acc2[r];
        accbuf[wave][row][3 * 16 + mq] = acc3[r];
        if (mq == 0) rowsums[wave][row] = accS[r];
    }
    __syncthreads();

    // combine 4 j-strips, divide by rowsum, coalesced float4 store
    {
        const int row = t >> 4, f0 = (t & 15) * 4;
        f32x4 o = {0.f, 0.f, 0.f, 0.f};
#pragma unroll
        for (int w = 0; w < 4; ++w) {
            const f32x4 p = *(const f32x4*)&accbuf[w][row][f0];
            o += p;
        }
        const float rs = rowsums[0][row] + rowsums[1][row] +
                         rowsums[2][row] + rowsums[3][row];
        const float inv = 1.0f / rs;
        o *= inv;
        *(f32x4*)&out[(size_t)(i0 + row) * F_OUT + f0] = o;
    }
}

extern "C" void kernel_launch(void* const* d_in, const int* in_sizes, int n_in,
                              void* d_out, int out_size, void* d_ws, size_t ws_size,
                              hipStream_t stream) {
    const float* h   = (const float*)d_in[0];
    const int*   adj = (const int*)d_in[1];
    const float* W   = (const float*)d_in[2];
    const float* a   = (const float*)d_in[3];
    float* out = (float*)d_out;

    // workspace: WhT bf16 [64][8192] (1 MB), s1 (32 KB), s2 (32 KB)
    unsigned short* WhT = (unsigned short*)d_ws;
    float* s1 = (float*)((char*)d_ws + (size_t)F_OUT * N * sizeof(unsigned short));
    float* s2 = s1 + N;

    wh_kernel<<<N / K1_ROWS, 256, 0, stream>>>(h, W, a, WhT, s1, s2);
    attn_kernel<<<N / ROWS2, 256, 0, stream>>>(adj, WhT, s1, s2, out);
}

// Round 4
// 453.711 us; speedup vs baseline: 2.4801x; 1.4227x over previous
//
#include <hip/hip_runtime.h>

#define N 8192
#define F_IN 256
#define F_OUT 64
#define ALPHA 0.2f

typedef __attribute__((ext_vector_type(8))) short bf16x8;
typedef __attribute__((ext_vector_type(4))) float f32x4;
typedef __attribute__((ext_vector_type(4))) unsigned u32x4;
typedef __attribute__((ext_vector_type(4))) unsigned short u16x4;

// f32 -> bf16 round-to-nearest-even (finite values only)
__device__ __forceinline__ unsigned short f2bf(float x) {
    unsigned u = __float_as_uint(x);
    u = (u + 0x7FFFu + ((u >> 16) & 1u)) >> 16;
    return (unsigned short)u;
}
__device__ __forceinline__ float bf2f(unsigned short h) {
    return __uint_as_float((unsigned)h << 16);
}

// ---------------------------------------------------------------------------
// prep: Wa1 = W@a1, Wa2 = W@a2 (fp32); WbT hi/lo bf16 split, [f][k]. 1 block.
// ---------------------------------------------------------------------------
__global__ __launch_bounds__(256) void prep_kernel(
    const float* __restrict__ W, const float* __restrict__ a,
    float* __restrict__ Wa1, float* __restrict__ Wa2,
    unsigned short* __restrict__ WbTh, unsigned short* __restrict__ WbTl) {
    __shared__ float Wl[F_IN][F_OUT + 1];
    __shared__ float al[2 * F_OUT];
    const int t = threadIdx.x;
    for (int it = 0; it < 16; ++it) {
        const int idx = it * 1024 + t * 4;
        const f32x4 v = *(const f32x4*)&W[idx];
        const int r = idx >> 6, c = idx & 63;
        Wl[r][c] = v[0]; Wl[r][c + 1] = v[1]; Wl[r][c + 2] = v[2]; Wl[r][c + 3] = v[3];
    }
    if (t < 128) al[t] = a[t];
    __syncthreads();
    float x1 = 0.f, x2 = 0.f;
#pragma unroll 8
    for (int f = 0; f < F_OUT; ++f) {
        const float wv = Wl[t][f];
        x1 += wv * al[f];
        x2 += wv * al[F_OUT + f];
    }
    Wa1[t] = x1; Wa2[t] = x2;
    const int f = t >> 2, k0 = (t & 3) * 64;
    for (int kk = 0; kk < 64; kk += 8) {
        u32x4 ph, pl;
#pragma unroll
        for (int u = 0; u < 4; ++u) {
            const float w0 = Wl[k0 + kk + 2 * u][f];
            const float w1 = Wl[k0 + kk + 2 * u + 1][f];
            const unsigned short h0 = f2bf(w0), h1 = f2bf(w1);
            const unsigned short l0 = f2bf(w0 - bf2f(h0)), l1 = f2bf(w1 - bf2f(h1));
            ph[u] = (unsigned)h0 | ((unsigned)h1 << 16);
            pl[u] = (unsigned)l0 | ((unsigned)l1 << 16);
        }
        *(u32x4*)&WbTh[f * F_IN + k0 + kk] = ph;
        *(u32x4*)&WbTl[f * F_IN + k0 + kk] = pl;
    }
}

// ---------------------------------------------------------------------------
// scores: s1[i] = h[i,:]@Wa1, s2[i] = h[i,:]@Wa2 (fp32 exact).
// ---------------------------------------------------------------------------
__global__ __launch_bounds__(256) void score_kernel(
    const float* __restrict__ h, const float* __restrict__ Wa1,
    const float* __restrict__ Wa2, float* __restrict__ s1, float* __restrict__ s2) {
    __shared__ float w1l[F_IN], w2l[F_IN];
    const int t = threadIdx.x, wave = t >> 6, lane = t & 63;
    w1l[t] = Wa1[t]; w2l[t] = Wa2[t];
    __syncthreads();
    const int row0 = blockIdx.x * 16 + wave * 4;
    const f32x4 wa1 = *(const f32x4*)&w1l[lane * 4];
    const f32x4 wa2 = *(const f32x4*)&w2l[lane * 4];
#pragma unroll
    for (int r = 0; r < 4; ++r) {
        const f32x4 hv = *(const f32x4*)(h + (size_t)(row0 + r) * F_IN + lane * 4);
        float d1 = hv[0] * wa1[0] + hv[1] * wa1[1] + hv[2] * wa1[2] + hv[3] * wa1[3];
        float d2 = hv[0] * wa2[0] + hv[1] * wa2[1] + hv[2] * wa2[2] + hv[3] * wa2[3];
#pragma unroll
        for (int off = 32; off; off >>= 1) {
            d1 += __shfl_down(d1, off, 64);
            d2 += __shfl_down(d2, off, 64);
        }
        if (lane == 0) { s1[row0 + r] = d1; s2[row0 + r] = d2; }
    }
}

// ---------------------------------------------------------------------------
// whT: WhT[f][i] = bf16((h@W)[i][f]) via hi/lo-split bf16 MFMA (3 products).
// grid 512 x 64 (1 wave = 16-row m-tile).
// ---------------------------------------------------------------------------
__global__ __launch_bounds__(64) void whT_kernel(
    const float* __restrict__ h, const unsigned short* __restrict__ WbTh,
    const unsigned short* __restrict__ WbTl, unsigned short* __restrict__ WhT) {
    const int lane = threadIdx.x;
    const int mq = lane & 15, quad = lane >> 4;
    const int i0 = blockIdx.x * 16;
    const float* hp = h + (size_t)(i0 + mq) * F_IN + quad * 8;
    const unsigned short* bph = WbTh + mq * F_IN + quad * 8;
    const unsigned short* bpl = WbTl + mq * F_IN + quad * 8;
    f32x4 acc[4] = {{0.f, 0.f, 0.f, 0.f}, {0.f, 0.f, 0.f, 0.f},
                    {0.f, 0.f, 0.f, 0.f}, {0.f, 0.f, 0.f, 0.f}};
#pragma unroll
    for (int kk = 0; kk < 8; ++kk) {
        const f32x4 h0 = *(const f32x4*)(hp + kk * 32);
        const f32x4 h1 = *(const f32x4*)(hp + kk * 32 + 4);
        bf16x8 ah, al;
#pragma unroll
        for (int u = 0; u < 8; ++u) {
            const float v = (u < 4) ? h0[u] : h1[u - 4];
            const unsigned short hi = f2bf(v);
            ah[u] = (short)hi;
            al[u] = (short)f2bf(v - bf2f(hi));
        }
#pragma unroll
        for (int nt = 0; nt < 4; ++nt) {
            const bf16x8 bh = *(const bf16x8*)(bph + nt * 16 * F_IN + kk * 32);
            const bf16x8 bl = *(const bf16x8*)(bpl + nt * 16 * F_IN + kk * 32);
            acc[nt] = __builtin_amdgcn_mfma_f32_16x16x32_bf16(ah, bh, acc[nt], 0, 0, 0);
            acc[nt] = __builtin_amdgcn_mfma_f32_16x16x32_bf16(al, bh, acc[nt], 0, 0, 0);
            acc[nt] = __builtin_amdgcn_mfma_f32_16x16x32_bf16(ah, bl, acc[nt], 0, 0, 0);
        }
    }
#pragma unroll
    for (int nt = 0; nt < 4; ++nt) {
        u16x4 o;
#pragma unroll
        for (int r = 0; r < 4; ++r) o[r] = f2bf(acc[nt][r]);
        *(u16x4*)&WhT[(size_t)(nt * 16 + mq) * N + i0 + quad * 4] = o;
    }
}

// ---------------------------------------------------------------------------
// attn: single kernel, adj read ONCE.
// Phase 1 (block-wide): stream 16-row adj strip -> nibble mask in LDS +
// per-row masked max of s2 (true masked max -> max weight = exp(0) = 1).
// Phase 2 (per wave, 1024-j strip): rebuild weights from LDS mask, 5x MFMA.
// grid 512 x 512 (8 waves), 2 blocks/CU.
// ---------------------------------------------------------------------------
#define AROWS 16
#define MROWB 2068   // 2048 mask bytes + 20 pad (word stride 517 -> spreads banks)
__global__ __launch_bounds__(512, 4) void attn_kernel(
    const int* __restrict__ adj, const unsigned short* __restrict__ WhT,
    const float* __restrict__ s1, const float* __restrict__ s2,
    float* __restrict__ out) {
    __shared__ unsigned char maskb[AROWS * MROWB];            // 33 KB
    __shared__ float partmax[AROWS][8];
    __shared__ float mrow[AROWS], s1l[AROWS];
    __shared__ __align__(16) float accbuf[8][AROWS][F_OUT];   // 32 KB
    __shared__ float rowsums[8][AROWS];

    const int t = threadIdx.x, wave = t >> 6, lane = t & 63;
    const int i0 = blockIdx.x * AROWS;

    // ---------------- phase 1: adj strip -> mask + masked s2 row max ----------------
    float rm[AROWS];
#pragma unroll
    for (int r = 0; r < AROWS; ++r) rm[r] = -3.0e38f;

#pragma unroll 1
    for (int u = 0; u < 2; ++u) {
        const int j = u * 4096 + t * 8;
        const f32x4 sv0 = *(const f32x4*)(s2 + j);
        const f32x4 sv1 = *(const f32x4*)(s2 + j + 4);
#pragma unroll 2
        for (int r = 0; r < AROWS; ++r) {
            const int* arow = adj + (size_t)(i0 + r) * N + j;
            const int4 a0 = *(const int4*)arow;
            const int4 a1 = *(const int4*)(arow + 4);
            unsigned m0 = (a0.x > 0 ? 1u : 0u) | (a0.y > 0 ? 2u : 0u) |
                          (a0.z > 0 ? 4u : 0u) | (a0.w > 0 ? 8u : 0u);
            unsigned m1 = (a1.x > 0 ? 1u : 0u) | (a1.y > 0 ? 2u : 0u) |
                          (a1.z > 0 ? 4u : 0u) | (a1.w > 0 ? 8u : 0u);
            float mx = -3.0e38f;
            mx = fmaxf(mx, a0.x > 0 ? sv0[0] : -3.0e38f);
            mx = fmaxf(mx, a0.y > 0 ? sv0[1] : -3.0e38f);
            mx = fmaxf(mx, a0.z > 0 ? sv0[2] : -3.0e38f);
            mx = fmaxf(mx, a0.w > 0 ? sv0[3] : -3.0e38f);
            mx = fmaxf(mx, a1.x > 0 ? sv1[0] : -3.0e38f);
            mx = fmaxf(mx, a1.y > 0 ? sv1[1] : -3.0e38f);
            mx = fmaxf(mx, a1.z > 0 ? sv1[2] : -3.0e38f);
            mx = fmaxf(mx, a1.w > 0 ? sv1[3] : -3.0e38f);
            *(unsigned short*)&maskb[r * MROWB + u * 1024 + t * 2] =
                (unsigned short)(m0 | (m1 << 8));
            rm[r] = fmaxf(rm[r], mx);
        }
    }
    // reduce per-row max: wave shuffle -> LDS -> final
#pragma unroll
    for (int r = 0; r < AROWS; ++r) {
        float v = rm[r];
#pragma unroll
        for (int off = 32; off; off >>= 1) v = fmaxf(v, __shfl_down(v, off, 64));
        if (lane == 0) partmax[r][wave] = v;
    }
    __syncthreads();
    if (t < AROWS) {
        float mm = partmax[t][0];
#pragma unroll
        for (int w = 1; w < 8; ++w) mm = fmaxf(mm, partmax[t][w]);
        const float s1v = s1[i0 + t];
        const float x = s1v + mm;          // true masked row max (pre-lrelu)
        mrow[t] = fmaxf(x, ALPHA * x);     // lrelu monotone -> true score max
        s1l[t] = s1v;
    }
    __syncthreads();

    // ---------------- phase 2: MFMA P @ WhT over this wave's 1024-j strip ----------------
    const int mq = lane & 15, quad = lane >> 4;
    const float s1m = s1l[mq];
    const float mr = mrow[mq];
    const int jb0 = wave * 1024;

    const float* sp = s2 + jb0 + quad * 8;
    const unsigned short* wp = WhT + (size_t)mq * N + jb0 + quad * 8;
    const unsigned char* mbp = &maskb[mq * MROWB + (jb0 >> 2) + quad * 2];

    f32x4 acc0 = {0.f, 0.f, 0.f, 0.f}, acc1 = acc0, acc2 = acc0, acc3 = acc0, accS = acc0;
    bf16x8 onesf;
#pragma unroll
    for (int u = 0; u < 8; ++u) onesf[u] = (mq == 0) ? (short)0x3F80 : (short)0;

    bf16x8 b0 = *(const bf16x8*)(wp);
    bf16x8 b1 = *(const bf16x8*)(wp + 16 * N);
    bf16x8 b2 = *(const bf16x8*)(wp + 32 * N);
    bf16x8 b3 = *(const bf16x8*)(wp + 48 * N);

    for (int c = 0; c < 32; ++c) {
        const int cn = (c + 1) & 31;   // wrap: last prefetch re-reads c=0 (in-bounds)
        const bf16x8 nb0 = *(const bf16x8*)(wp + cn * 32);
        const bf16x8 nb1 = *(const bf16x8*)(wp + cn * 32 + 16 * N);
        const bf16x8 nb2 = *(const bf16x8*)(wp + cn * 32 + 32 * N);
        const bf16x8 nb3 = *(const bf16x8*)(wp + cn * 32 + 48 * N);

        const unsigned mw = *(const unsigned short*)(mbp + c * 8);
        const unsigned mbyte = (mw & 0xFu) | ((mw >> 4) & 0xF0u);
        const f32x4 v0 = *(const f32x4*)(sp + c * 32);
        const f32x4 v1 = *(const f32x4*)(sp + c * 32 + 4);

        bf16x8 af;
#pragma unroll
        for (int jj = 0; jj < 8; ++jj) {
            const float s2k = (jj < 4) ? v0[jj] : v1[jj - 4];
            const float x = s1m + s2k;
            const float e = fmaxf(x, ALPHA * x);
            const float w = ((mbyte >> jj) & 1u) ? __expf(e - mr) : 0.f;  // <= 1
            af[jj] = (short)f2bf(w);
        }
        acc0 = __builtin_amdgcn_mfma_f32_16x16x32_bf16(af, b0, acc0, 0, 0, 0);
        acc1 = __builtin_amdgcn_mfma_f32_16x16x32_bf16(af, b1, acc1, 0, 0, 0);
        acc2 = __builtin_amdgcn_mfma_f32_16x16x32_bf16(af, b2, acc2, 0, 0, 0);
        acc3 = __builtin_amdgcn_mfma_f32_16x16x32_bf16(af, b3, acc3, 0, 0, 0);
        accS = __builtin_amdgcn_mfma_f32_16x16x32_bf16(af, onesf, accS, 0, 0, 0);
        b0 = nb0; b1 = nb1; b2 = nb2; b3 = nb3;
    }

#pragma unroll
    for (int r = 0; r < 4; ++r) {
        const int row = quad * 4 + r;
        accbuf[wave][row][0 + mq]  = acc0[r];
        accbuf[wave][row][16 + mq] = acc1[r];
        accbuf[wave][row][32 + mq] = acc2[r];
        accbuf[wave][row][48 + mq] = acc3[r];
        if (mq == 0) rowsums[wave][row] = accS[r];
    }
    __syncthreads();

    {
        const int row = t >> 5, f0 = (t & 31) * 2;
        float o0 = 0.f, o1 = 0.f, rs = 0.f;
#pragma unroll
        for (int w = 0; w < 8; ++w) {
            o0 += accbuf[w][row][f0];
            o1 += accbuf[w][row][f0 + 1];
            rs += rowsums[w][row];
        }
        const float inv = (rs > 0.f) ? 1.f / rs : 0.f;   // guard impossible all-masked row
        float2 st = {o0 * inv, o1 * inv};
        *(float2*)&out[(size_t)(i0 + row) * F_OUT + f0] = st;
    }
}

extern "C" void kernel_launch(void* const* d_in, const int* in_sizes, int n_in,
                              void* d_out, int out_size, void* d_ws, size_t ws_size,
                              hipStream_t stream) {
    const float* h   = (const float*)d_in[0];
    const int*   adj = (const int*)d_in[1];
    const float* W   = (const float*)d_in[2];
    const float* a   = (const float*)d_in[3];
    float* out = (float*)d_out;

    char* ws = (char*)d_ws;
    unsigned short* WhT = (unsigned short*)ws;                   // 1 MB
    float* s1  = (float*)(ws + (size_t)F_OUT * N * 2);           // 32 KB
    float* s2  = s1 + N;                                         // 32 KB
    float* Wa1 = s2 + N;
    float* Wa2 = Wa1 + F_IN;
    unsigned short* WbTh = (unsigned short*)(Wa2 + F_IN);        // 32 KB
    unsigned short* WbTl = WbTh + F_OUT * F_IN;                  // 32 KB

    prep_kernel<<<1, 256, 0, stream>>>(W, a, Wa1, Wa2, WbTh, WbTl);
    score_kernel<<<N / 16, 256, 0, stream>>>(h, Wa1, Wa2, s1, s2);
    whT_kernel<<<N / 16, 64, 0, stream>>>(h, WbTh, WbTl, WhT);
    attn_kernel<<<N / AROWS, 512, 0, stream>>>(adj, WhT, s1, s2, out);
}